// Round 4
// baseline (175.775 us; speedup 1.0000x reference)
//
#include <hip/hip_runtime.h>
#include <hip/hip_bf16.h>
#include <cstdint>
#include <cstddef>

#define NS_ROWS 4096
#define NT_ROWS 4096
#define DIM 1024
#define NC 4
#define NWORK_MAX 2432

typedef __attribute__((ext_vector_type(8))) short bf16x8;
typedef __attribute__((ext_vector_type(4))) float f32x4;

#define GLOBAL_AS __attribute__((address_space(1)))
#define LDS_AS __attribute__((address_space(3)))

// ---------------- ws layout ----------------
// fs (bf16, class-permuted source rows)   @ 0         8,388,608 B
// ft (bf16, class-permuted target rows)   @ 8388608   8,388,608 B
// nS,wS,cS,nT,wT,cT : 6 arrays of 4096x4B @ 16777216  (16 KB each)
// clsT_tmp (i32), wt2_tmp (f32)           : 2 x 16 KB (unpermuted target prep)
// ctrl ints [28]: [0..3]cntS [4..7]cntT [8..11]curS [12..15]curT
//                 [16..19]baseS [20..23]baseT [24]nwork
// acc floats [26]: [0]ce [1]ent [10..13]tr_t [14..17]ss_s [18..21]ss_t [22..25]ss_st
// worklist int4 x NWORK_MAX
#define ACC_N 26

__device__ __forceinline__ float bf16_round(float x, unsigned short* bits) {
    uint32_t u = __float_as_uint(x);
    uint32_t b = (u + 0x7FFFu + ((u >> 16) & 1u)) >> 16;   // RNE
    *bits = (unsigned short)b;
    return __uint_as_float(b << 16);
}

// Per-row logits work: CE(source), entropy/pseudo/w2 (target), class counts.
__global__ void prep_rows(const float* __restrict__ LS, const int* __restrict__ labels,
                          const float* __restrict__ LT, int* __restrict__ clsT_tmp,
                          float* __restrict__ wt2_tmp, int* __restrict__ ctrl,
                          float* __restrict__ acc) {
    __shared__ float sacc[ACC_N];
    __shared__ int scnt[8];
    int t = threadIdx.x;
    if (t < ACC_N) sacc[t] = 0.f;
    if (t < 8) scnt[t] = 0;
    __syncthreads();
    int gid = blockIdx.x * 256 + t;
    const float EPSF = 1e-8f;
    if (gid < NS_ROWS) {
        float4 l = ((const float4*)LS)[gid];
        float m = fmaxf(fmaxf(l.x, l.y), fmaxf(l.z, l.w));
        float e = expf(l.x - m) + expf(l.y - m) + expf(l.z - m) + expf(l.w - m);
        float lse = m + logf(e);
        int lab = labels[gid];
        float ll = (lab == 0) ? l.x : (lab == 1) ? l.y : (lab == 2) ? l.z : l.w;
        atomicAdd(&sacc[0], lse - ll);
        atomicAdd(&scnt[lab], 1);
    } else {
        int j = gid - NS_ROWS;
        float4 l = ((const float4*)LT)[j];
        float m = fmaxf(fmaxf(l.x, l.y), fmaxf(l.z, l.w));
        float p0 = expf(l.x - m), p1 = expf(l.y - m), p2 = expf(l.z - m), p3 = expf(l.w - m);
        float s = p0 + p1 + p2 + p3;
        p0 /= s; p1 /= s; p2 /= s; p3 /= s;
        float ent = p0 * logf(p0 + EPSF) + p1 * logf(p1 + EPSF) +
                    p2 * logf(p2 + EPSF) + p3 * logf(p3 + EPSF);
        int am = 0; float bm = p0;
        if (p1 > bm) { bm = p1; am = 1; }
        if (p2 > bm) { bm = p2; am = 2; }
        if (p3 > bm) { bm = p3; am = 3; }
        float sumsq = p0 * p0 + p1 * p1 + p2 * p2 + p3 * p3;
        const float INV_LOG2 = 1.44269504088896340736f;
        float h2 = -logf(sumsq + EPSF) * INV_LOG2;
        float w = 1.0f - h2 / (2.0f + EPSF);
        float w2 = w * w;
        clsT_tmp[j] = am;
        wt2_tmp[j] = w2;
        atomicAdd(&sacc[1], ent);
        atomicAdd(&scnt[4 + am], 1);
        atomicAdd(&sacc[10 + am], w2);
    }
    __syncthreads();
    if (t < ACC_N && sacc[t] != 0.f) atomicAdd(&acc[t], sacc[t]);
    if (t < 8 && scnt[t] != 0) atomicAdd(&ctrl[t], scnt[t]);
}

// Build segment bases + per-class tile work list (serial on one thread; ~700 items).
__global__ void aux_build(int* __restrict__ ctrl, int4* __restrict__ wl) {
    if (threadIdx.x != 0) return;
    int Ts[NC], Tt[NC];
    int bs = 0, bt = 0;
    for (int c = 0; c < NC; ++c) {
        int ns = ctrl[c], nt = ctrl[4 + c];
        ctrl[16 + c] = bs; ctrl[20 + c] = bt;
        Ts[c] = (ns + 127) >> 7;
        Tt[c] = (nt + 127) >> 7;
        bs += ns; bt += nt;
    }
    int n = 0;
    for (int c = 0; c < NC; ++c)
        for (int tj = 0; tj < Ts[c]; ++tj)
            for (int ti = 0; ti <= tj; ++ti) wl[n++] = make_int4(0, c, ti, tj);
    for (int c = 0; c < NC; ++c)
        for (int tj = 0; tj < Tt[c]; ++tj)
            for (int ti = 0; ti <= tj; ++ti) wl[n++] = make_int4(1, c, ti, tj);
    for (int c = 0; c < NC; ++c)
        for (int ti = 0; ti < Ts[c]; ++ti)
            for (int tj = 0; tj < Tt[c]; ++tj) wl[n++] = make_int4(2, c, ti, tj);
    ctrl[24] = n;   // provably <= 2380 < NWORK_MAX
}

// bf16-convert + row norms, scattered to class-contiguous permuted buffers.
// One block (128 threads) per row; slot via per-class atomic cursor.
__global__ void scatter_feat(const float* __restrict__ FS, const float* __restrict__ FT,
                             const int* __restrict__ labels,
                             const int* __restrict__ clsT_tmp, const float* __restrict__ wt2_tmp,
                             int* __restrict__ ctrl,
                             unsigned short* __restrict__ fs, unsigned short* __restrict__ ft,
                             float* __restrict__ nS, float* __restrict__ wS, int* __restrict__ cS,
                             float* __restrict__ nT, float* __restrict__ wT, int* __restrict__ cT) {
    int b = blockIdx.x;
    int t = threadIdx.x;
    bool isS = b < NS_ROWS;
    int r = isS ? b : b - NS_ROWS;
    int cls = isS ? labels[r] : clsT_tmp[r];
    __shared__ int sdst;
    __shared__ float partial[2];
    if (t == 0) {
        int* cursor = ctrl + (isS ? 8 : 12);
        int base = ctrl[(isS ? 16 : 20) + cls];
        sdst = base + atomicAdd(&cursor[cls], 1);
    }
    const float* src = (isS ? FS : FT) + (size_t)r * DIM;
    float4 v0 = ((const float4*)src)[t * 2];
    float4 v1 = ((const float4*)src)[t * 2 + 1];
    float vals[8] = {v0.x, v0.y, v0.z, v0.w, v1.x, v1.y, v1.z, v1.w};
    unsigned short us[8];
    float ssum = 0.f;
#pragma unroll
    for (int i = 0; i < 8; ++i) {
        float f = bf16_round(vals[i], &us[i]);
        ssum += f * f;
    }
    for (int off = 32; off; off >>= 1) ssum += __shfl_xor(ssum, off);
    if ((t & 63) == 0) partial[t >> 6] = ssum;
    __syncthreads();
    int dst = sdst;
    bf16x8 pack;
#pragma unroll
    for (int i = 0; i < 8; ++i) pack[i] = (short)us[i];
    unsigned short* fdst = (isS ? fs : ft) + (size_t)dst * DIM;
    *(bf16x8*)(fdst + (size_t)t * 8) = pack;
    if (t == 0) {
        float nrm = partial[0] + partial[1];
        if (isS) { nS[dst] = nrm; wS[dst] = 1.0f; cS[dst] = cls; }
        else     { nT[dst] = nrm; wT[dst] = wt2_tmp[r]; cT[dst] = cls; }
    }
}

// Fused GEMM (A@B^T) + RBF + weighted reduction over class-partitioned tiles.
// 128x128 tile, 4 waves (2x2 of 64x64), BK=32, mfma 16x16x32 bf16,
// 2-phase double-buffered pipeline. Work item: {kind, cls, ti, tj}.
__global__ __launch_bounds__(256, 4)
void gemm_reduce(const unsigned short* __restrict__ fs, const unsigned short* __restrict__ ft,
                 const float* __restrict__ nS, const float* __restrict__ wS, const int* __restrict__ cS,
                 const float* __restrict__ nT, const float* __restrict__ wT, const int* __restrict__ cT,
                 const int* __restrict__ ctrl, const int4* __restrict__ wl,
                 float* __restrict__ acc) {
    __shared__ unsigned short As[2][128 * 32];
    __shared__ unsigned short Bs[2][128 * 32];
    __shared__ float sred;

    int nwork = ctrl[24];
    int bid = blockIdx.x;
    if (bid >= nwork) return;
    int4 it = wl[bid];
    int kind = it.x, cls = it.y, ti = it.z, tj = it.w;

    const unsigned short *A, *B;
    const float *nA, *nB, *wA, *wB;
    const int *cA, *cB;
    int baseA, baseB;
    if (kind == 0)      { A = fs; B = fs; nA = nS; nB = nS; wA = wS; wB = wS; cA = cS; cB = cS;
                          baseA = ctrl[16 + cls]; baseB = baseA; }
    else if (kind == 1) { A = ft; B = ft; nA = nT; nB = nT; wA = wT; wB = wT; cA = cT; cB = cT;
                          baseA = ctrl[20 + cls]; baseB = baseA; }
    else                { A = fs; B = ft; nA = nS; nB = nT; wA = wS; cA = cS; cB = cT;
                          // FIX (R3 bug): reference ss_st uses UNWEIGHTED masks on both
                          // sides (Ms, Mt) — no w^2 on the target side. wS is all-ones
                          // over [0,4096), so it serves as the ones-array for B too.
                          wB = wS;
                          baseA = ctrl[16 + cls]; baseB = ctrl[20 + cls]; }
    float* outp = acc + 14 + kind * 4 + cls;
    float factor = (kind != 2 && ti != tj) ? 2.0f : 1.0f;

    int tid = threadIdx.x;
    int lane = tid & 63;
    int wid = tid >> 6;
    int wr = wid >> 1, wc = wid & 1;

    int rowA0 = baseA + ti * 128;
    int rowB0 = baseB + tj * 128;

    int srow = tid >> 2;                // 0..63
    int scol = (tid & 3) * 8;           // 0,8,16,24 (shorts)

    // clamped (<=4095) staging row pointers; OOB rows masked in epilogue
    const unsigned short* pa0 = A + (size_t)min(rowA0 + srow,      4095) * DIM + scol;
    const unsigned short* pa1 = A + (size_t)min(rowA0 + srow + 64, 4095) * DIM + scol;
    const unsigned short* pb0 = B + (size_t)min(rowB0 + srow,      4095) * DIM + scol;
    const unsigned short* pb1 = B + (size_t)min(rowB0 + srow + 64, 4095) * DIM + scol;

    f32x4 accf[4][4];
#pragma unroll
    for (int m = 0; m < 4; ++m)
#pragma unroll
        for (int n = 0; n < 4; ++n) accf[m][n] = (f32x4)(0.f);

    int lr = lane & 15;
    int lk = (lane >> 4) * 8;

#define STAGE(buf, kt)                                                            \
    do {                                                                          \
        int k0_ = (kt) * 32;                                                      \
        __builtin_amdgcn_global_load_lds((const GLOBAL_AS void*)(pa0 + k0_),      \
            (LDS_AS void*)(As[buf] + tid * 8), 16, 0, 0);                         \
        __builtin_amdgcn_global_load_lds((const GLOBAL_AS void*)(pa1 + k0_),      \
            (LDS_AS void*)(As[buf] + 2048 + tid * 8), 16, 0, 0);                  \
        __builtin_amdgcn_global_load_lds((const GLOBAL_AS void*)(pb0 + k0_),      \
            (LDS_AS void*)(Bs[buf] + tid * 8), 16, 0, 0);                         \
        __builtin_amdgcn_global_load_lds((const GLOBAL_AS void*)(pb1 + k0_),      \
            (LDS_AS void*)(Bs[buf] + 2048 + tid * 8), 16, 0, 0);                  \
    } while (0)

#define COMPUTE(buf)                                                              \
    do {                                                                          \
        bf16x8 af[4], bfr[4];                                                     \
        _Pragma("unroll")                                                         \
        for (int f = 0; f < 4; ++f)                                               \
            af[f] = *(const bf16x8*)(As[buf] + (wr * 64 + f * 16 + lr) * 32 + lk);\
        _Pragma("unroll")                                                         \
        for (int f = 0; f < 4; ++f)                                               \
            bfr[f] = *(const bf16x8*)(Bs[buf] + (wc * 64 + f * 16 + lr) * 32 + lk);\
        _Pragma("unroll")                                                         \
        for (int m = 0; m < 4; ++m)                                               \
            _Pragma("unroll")                                                     \
            for (int n = 0; n < 4; ++n)                                           \
                accf[m][n] = __builtin_amdgcn_mfma_f32_16x16x32_bf16(             \
                    af[m], bfr[n], accf[m][n], 0, 0, 0);                          \
    } while (0)

    STAGE(0, 0);
    asm volatile("s_waitcnt vmcnt(0)");
    __syncthreads();

    int cur = 0;
    for (int kt = 0; kt < DIM / 32 - 1; ++kt) {
        STAGE(cur ^ 1, kt + 1);     // next tile's loads fly during compute
        COMPUTE(cur);
        __syncthreads();            // drains vmcnt(0)+lgkmcnt(0); next buf ready
        cur ^= 1;
    }
    COMPUTE(cur);

    // ---- fused epilogue: d2 -> K^2 -> weighted accumulate (single scalar) ----
    int rowBase = rowA0 + wr * 64;
    int colBase = rowB0 + wc * 64;

    float cn[4], cw[4];
#pragma unroll
    for (int f = 0; f < 4; ++f) {
        int gj = colBase + f * 16 + lr;
        int gjc = min(gj, 4095);
        cn[f] = nB[gjc];
        cw[f] = (gj < 4096 && cB[gjc] == cls) ? wB[gjc] : 0.0f;
    }

    const float NEGF = (-2.0f / (2.0f * 32.0f * 32.0f + 1e-8f)) * 1.44269504088896340736f;
    float lacc = 0.f;

#pragma unroll
    for (int m = 0; m < 4; ++m) {
#pragma unroll
        for (int j = 0; j < 4; ++j) {
            int gi = rowBase + m * 16 + (lane >> 4) * 4 + j;
            int gic = min(gi, 4095);
            float rn = nA[gic];
            float rw = (gi < 4096 && cA[gic] == cls) ? wA[gic] : 0.0f;
#pragma unroll
            for (int n = 0; n < 4; ++n) {
                float dot = accf[m][n][j];
                float d2 = rn + cn[n] - 2.0f * dot;
                d2 = fmaxf(d2, 0.0f);
                float k2 = exp2f(d2 * NEGF);        // = K^2
                lacc += k2 * rw * cw[n];
            }
        }
    }

    if (tid == 0) sred = 0.f;
    __syncthreads();
    for (int off = 32; off; off >>= 1) lacc += __shfl_xor(lacc, off);
    if (lane == 0) atomicAdd(&sred, lacc);
    __syncthreads();
    if (tid == 0) atomicAdd(outp, factor * sred);
#undef STAGE
#undef COMPUTE
}

__global__ void finalize_kernel(const float* __restrict__ acc, const int* __restrict__ ctrl,
                                float* __restrict__ out) {
    if (threadIdx.x != 0 || blockIdx.x != 0) return;
    const double EPS = 1e-8;
    const double LOG2 = 0.6931471805599453;
    double loss_cls = (double)acc[0] / NS_ROWS;
    double loss_ent = -(double)acc[1] / NT_ROWS;
    double creda_sum = 0.0, n_valid = 0.0;
    for (int c = 0; c < NC; ++c) {
        int nsc_i = ctrl[c], ntc_i = ctrl[4 + c];
        double nsc = (double)nsc_i, trt = acc[10 + c];
        double sss = acc[14 + c], sst = acc[18 + c], ssst = acc[22 + c];
        double trs = nsc;
        double info_s = sss / ((trs + EPS) * (trs + EPS));
        double h_s = -log(info_s + EPS) / LOG2;
        double info_t = sst / ((trt + EPS) * (trt + EPS));
        double h_t = -log(info_t + EPS) / LOG2;
        double trm = trs + trt;
        double ssm = sss + 2.0 * ssst + sst;
        double info_m = ssm / ((trm + EPS) * (trm + EPS));
        double h_m = -log(info_m + EPS) / LOG2;
        double pc = h_m - 0.5 * (h_s + h_t);
        if (nsc_i >= 2 && ntc_i >= 2) { creda_sum += pc; n_valid += 1.0; }
    }
    double creda = (n_valid > 0.0) ? creda_sum / n_valid : 0.0;
    out[0] = (float)(loss_cls + 1.0 * creda + 0.1 * loss_ent);
}

extern "C" void kernel_launch(void* const* d_in, const int* in_sizes, int n_in,
                              void* d_out, int out_size, void* d_ws, size_t ws_size,
                              hipStream_t stream) {
    const float* FS = (const float*)d_in[0];
    const float* LS = (const float*)d_in[1];
    const float* FT = (const float*)d_in[2];
    const float* LT = (const float*)d_in[3];
    const int* LAB = (const int*)d_in[4];

    char* ws = (char*)d_ws;
    unsigned short* fs = (unsigned short*)(ws);                       // 8 MB
    unsigned short* ft = (unsigned short*)(ws + 8388608);             // 8 MB
    char* p = ws + 16777216;
    float* nS  = (float*)(p);              // 16 KB
    float* wS  = (float*)(p + 16384);
    int*   cS  = (int*)  (p + 32768);
    float* nT  = (float*)(p + 49152);
    float* wT  = (float*)(p + 65536);
    int*   cT  = (int*)  (p + 81920);
    int*   clsT_tmp = (int*)  (p + 98304);
    float* wt2_tmp  = (float*)(p + 114688);
    int*   ctrl = (int*)  (p + 131072);    // 28 ints
    float* acc  = (float*)(p + 131072 + 128);  // 26 floats
    int4*  wl   = (int4*) (p + 131072 + 512);  // NWORK_MAX x 16 B

    hipMemsetAsync(ctrl, 0, 256, stream);  // zeroes ctrl (counts/cursors) + acc

    prep_rows<<<32, 256, 0, stream>>>(LS, LAB, LT, clsT_tmp, wt2_tmp, ctrl, acc);
    aux_build<<<1, 64, 0, stream>>>(ctrl, wl);
    scatter_feat<<<NS_ROWS + NT_ROWS, 128, 0, stream>>>(FS, FT, LAB, clsT_tmp, wt2_tmp,
                                                        ctrl, fs, ft,
                                                        nS, wS, cS, nT, wT, cT);
    gemm_reduce<<<NWORK_MAX, 256, 0, stream>>>(fs, ft, nS, wS, cS, nT, wT, cT,
                                               ctrl, wl, acc);
    finalize_kernel<<<1, 1, 0, stream>>>(acc, ctrl, (float*)d_out);
}

// Round 5
// 90.870 us; speedup vs baseline: 1.9344x; 1.9344x over previous
//
#include <hip/hip_runtime.h>
#include <hip/hip_bf16.h>
#include <cstdint>
#include <cstddef>

#define NS_ROWS 4096
#define NT_ROWS 4096
#define DIM 1024
#define NC 4
#define NWORK_MAX 2432

typedef __attribute__((ext_vector_type(8))) short bf16x8;
typedef __attribute__((ext_vector_type(4))) float f32x4;

#define GLOBAL_AS __attribute__((address_space(1)))
#define LDS_AS __attribute__((address_space(3)))

// ---------------- ws layout ----------------
// fs (bf16, class-permuted source rows)   @ 0         8,388,608 B
// ft (bf16, class-permuted target rows)   @ 8388608   8,388,608 B
// p = ws + 16777216:
//   nS@0 wS@16K cS@32K nT@48K wT@64K cT@80K clsT_tmp@96K wt2_tmp@112K  (16 KB each)
//   ctrl@128K (28 ints)  acc@128K+128 (26 f)  wl@128K+512 (NWORK_MAX int4)
//   dstS@128K+512+38912  dstT@+16K
// ctrl ints: [0..3]cntS [4..7]cntT [8..15]unused [16..19]baseS [20..23]baseT [24]nwork
#define ACC_N 26

__device__ __forceinline__ float bf16_round(float x, unsigned short* bits) {
    uint32_t u = __float_as_uint(x);
    uint32_t b = (u + 0x7FFFu + ((u >> 16) & 1u)) >> 16;   // RNE
    *bits = (unsigned short)b;
    return __uint_as_float(b << 16);
}

// Per-row logits work: CE(source), entropy/pseudo/w2 (target), class counts.
__global__ void prep_rows(const float* __restrict__ LS, const int* __restrict__ labels,
                          const float* __restrict__ LT, int* __restrict__ clsT_tmp,
                          float* __restrict__ wt2_tmp, int* __restrict__ ctrl,
                          float* __restrict__ acc) {
    __shared__ float sacc[ACC_N];
    __shared__ int scnt[8];
    int t = threadIdx.x;
    if (t < ACC_N) sacc[t] = 0.f;
    if (t < 8) scnt[t] = 0;
    __syncthreads();
    int gid = blockIdx.x * 256 + t;
    const float EPSF = 1e-8f;
    if (gid < NS_ROWS) {
        float4 l = ((const float4*)LS)[gid];
        float m = fmaxf(fmaxf(l.x, l.y), fmaxf(l.z, l.w));
        float e = expf(l.x - m) + expf(l.y - m) + expf(l.z - m) + expf(l.w - m);
        float lse = m + logf(e);
        int lab = labels[gid];
        float ll = (lab == 0) ? l.x : (lab == 1) ? l.y : (lab == 2) ? l.z : l.w;
        atomicAdd(&sacc[0], lse - ll);
        atomicAdd(&scnt[lab], 1);
    } else {
        int j = gid - NS_ROWS;
        float4 l = ((const float4*)LT)[j];
        float m = fmaxf(fmaxf(l.x, l.y), fmaxf(l.z, l.w));
        float p0 = expf(l.x - m), p1 = expf(l.y - m), p2 = expf(l.z - m), p3 = expf(l.w - m);
        float s = p0 + p1 + p2 + p3;
        p0 /= s; p1 /= s; p2 /= s; p3 /= s;
        float ent = p0 * logf(p0 + EPSF) + p1 * logf(p1 + EPSF) +
                    p2 * logf(p2 + EPSF) + p3 * logf(p3 + EPSF);
        int am = 0; float bm = p0;
        if (p1 > bm) { bm = p1; am = 1; }
        if (p2 > bm) { bm = p2; am = 2; }
        if (p3 > bm) { bm = p3; am = 3; }
        float sumsq = p0 * p0 + p1 * p1 + p2 * p2 + p3 * p3;
        const float INV_LOG2 = 1.44269504088896340736f;
        float h2 = -logf(sumsq + EPSF) * INV_LOG2;
        float w = 1.0f - h2 / (2.0f + EPSF);
        float w2 = w * w;
        clsT_tmp[j] = am;
        wt2_tmp[j] = w2;
        atomicAdd(&sacc[1], ent);
        atomicAdd(&scnt[4 + am], 1);
        atomicAdd(&sacc[10 + am], w2);
    }
    __syncthreads();
    if (t < ACC_N && sacc[t] != 0.f) atomicAdd(&acc[t], sacc[t]);
    if (t < 8 && scnt[t] != 0) atomicAdd(&ctrl[t], scnt[t]);
}

// Build segment bases + per-class tile work list (serial on one thread; ~700 items).
__global__ void aux_build(int* __restrict__ ctrl, int4* __restrict__ wl) {
    if (threadIdx.x != 0) return;
    int Ts[NC], Tt[NC];
    int bs = 0, bt = 0;
    for (int c = 0; c < NC; ++c) {
        int ns = ctrl[c], nt = ctrl[4 + c];
        ctrl[16 + c] = bs; ctrl[20 + c] = bt;
        Ts[c] = (ns + 127) >> 7;
        Tt[c] = (nt + 127) >> 7;
        bs += ns; bt += nt;
    }
    int n = 0;
    for (int c = 0; c < NC; ++c)
        for (int tj = 0; tj < Ts[c]; ++tj)
            for (int ti = 0; ti <= tj; ++ti) wl[n++] = make_int4(0, c, ti, tj);
    for (int c = 0; c < NC; ++c)
        for (int tj = 0; tj < Tt[c]; ++tj)
            for (int ti = 0; ti <= tj; ++ti) wl[n++] = make_int4(1, c, ti, tj);
    for (int c = 0; c < NC; ++c)
        for (int ti = 0; ti < Ts[c]; ++ti)
            for (int tj = 0; tj < Tt[c]; ++tj) wl[n++] = make_int4(2, c, ti, tj);
    ctrl[24] = n;   // provably <= 2380 < NWORK_MAX
}

// Deterministic counting-sort rank: dst[r] = classBase[cls] + (#rows j<r with same cls).
// grid = 2 blocks (0: source, 1: target) x 1024 threads; 4 rows/thread.
// Per-class counts packed 4x16-bit in a uint64; Hillis-Steele block scan in LDS.
__global__ void rank_rows(const int* __restrict__ labels, const int* __restrict__ clsT_tmp,
                          const int* __restrict__ ctrl,
                          int* __restrict__ dstS, int* __restrict__ dstT) {
    __shared__ unsigned long long sdata[1024];
    int t = threadIdx.x;
    bool isS = (blockIdx.x == 0);
    const int* cls = isS ? labels : clsT_tmp;
    int* dst = isS ? dstS : dstT;
    int baseOff = isS ? 16 : 20;

    int c4[4];
    unsigned long long packed = 0ULL;
#pragma unroll
    for (int i = 0; i < 4; ++i) {
        c4[i] = cls[t * 4 + i];
        packed += 1ULL << (c4[i] * 16);
    }
    sdata[t] = packed;
    __syncthreads();
    for (int off = 1; off < 1024; off <<= 1) {
        unsigned long long v = sdata[t];
        unsigned long long add = (t >= off) ? sdata[t - off] : 0ULL;
        __syncthreads();
        sdata[t] = v + add;
        __syncthreads();
    }
    unsigned long long ex = (t > 0) ? sdata[t - 1] : 0ULL;   // exclusive prefix
    int pref[4];
#pragma unroll
    for (int c = 0; c < NC; ++c)
        pref[c] = (int)((ex >> (c * 16)) & 0xFFFFULL) + ctrl[baseOff + c];
#pragma unroll
    for (int i = 0; i < 4; ++i) {
        int c = c4[i];
        dst[t * 4 + i] = pref[c]++;
    }
}

// bf16-convert + row norms, scattered to class-contiguous permuted buffers
// via the precomputed deterministic rank (NO atomics).
__global__ void scatter_feat(const float* __restrict__ FS, const float* __restrict__ FT,
                             const int* __restrict__ labels,
                             const int* __restrict__ clsT_tmp, const float* __restrict__ wt2_tmp,
                             const int* __restrict__ dstS, const int* __restrict__ dstT,
                             unsigned short* __restrict__ fs, unsigned short* __restrict__ ft,
                             float* __restrict__ nS, float* __restrict__ wS, int* __restrict__ cS,
                             float* __restrict__ nT, float* __restrict__ wT, int* __restrict__ cT) {
    int b = blockIdx.x;
    int t = threadIdx.x;
    bool isS = b < NS_ROWS;
    int r = isS ? b : b - NS_ROWS;
    int cls = isS ? labels[r] : clsT_tmp[r];
    int dst = isS ? dstS[r] : dstT[r];
    __shared__ float partial[2];
    const float* src = (isS ? FS : FT) + (size_t)r * DIM;
    float4 v0 = ((const float4*)src)[t * 2];
    float4 v1 = ((const float4*)src)[t * 2 + 1];
    float vals[8] = {v0.x, v0.y, v0.z, v0.w, v1.x, v1.y, v1.z, v1.w};
    unsigned short us[8];
    float ssum = 0.f;
#pragma unroll
    for (int i = 0; i < 8; ++i) {
        float f = bf16_round(vals[i], &us[i]);
        ssum += f * f;
    }
    bf16x8 pack;
#pragma unroll
    for (int i = 0; i < 8; ++i) pack[i] = (short)us[i];
    unsigned short* fdst = (isS ? fs : ft) + (size_t)dst * DIM;
    *(bf16x8*)(fdst + (size_t)t * 8) = pack;

    for (int off = 32; off; off >>= 1) ssum += __shfl_xor(ssum, off);
    if ((t & 63) == 0) partial[t >> 6] = ssum;
    __syncthreads();
    if (t == 0) {
        float nrm = partial[0] + partial[1];
        if (isS) { nS[dst] = nrm; wS[dst] = 1.0f; cS[dst] = cls; }
        else     { nT[dst] = nrm; wT[dst] = wt2_tmp[r]; cT[dst] = cls; }
    }
}

// Fused GEMM (A@B^T) + RBF + weighted reduction over class-partitioned tiles.
// 128x128 tile, 4 waves (2x2 of 64x64), BK=32, mfma 16x16x32 bf16,
// 2-phase double-buffered pipeline. Work item: {kind, cls, ti, tj}.
__global__ __launch_bounds__(256, 4)
void gemm_reduce(const unsigned short* __restrict__ fs, const unsigned short* __restrict__ ft,
                 const float* __restrict__ nS, const float* __restrict__ wS, const int* __restrict__ cS,
                 const float* __restrict__ nT, const float* __restrict__ wT, const int* __restrict__ cT,
                 const int* __restrict__ ctrl, const int4* __restrict__ wl,
                 float* __restrict__ acc) {
    __shared__ unsigned short As[2][128 * 32];
    __shared__ unsigned short Bs[2][128 * 32];
    __shared__ float sred;

    int nwork = ctrl[24];
    int bid = blockIdx.x;
    if (bid >= nwork) return;
    int4 it = wl[bid];
    int kind = it.x, cls = it.y, ti = it.z, tj = it.w;

    const unsigned short *A, *B;
    const float *nA, *nB, *wA, *wB;
    const int *cA, *cB;
    int baseA, baseB;
    if (kind == 0)      { A = fs; B = fs; nA = nS; nB = nS; wA = wS; wB = wS; cA = cS; cB = cS;
                          baseA = ctrl[16 + cls]; baseB = baseA; }
    else if (kind == 1) { A = ft; B = ft; nA = nT; nB = nT; wA = wT; wB = wT; cA = cT; cB = cT;
                          baseA = ctrl[20 + cls]; baseB = baseA; }
    else                { A = fs; B = ft; nA = nS; nB = nT; wA = wS; cA = cS; cB = cT;
                          // reference ss_st uses UNWEIGHTED masks on both sides (Ms, Mt);
                          // wS is all-ones so it serves as the ones-array for B too.
                          wB = wS;
                          baseA = ctrl[16 + cls]; baseB = ctrl[20 + cls]; }
    float* outp = acc + 14 + kind * 4 + cls;
    float factor = (kind != 2 && ti != tj) ? 2.0f : 1.0f;

    int tid = threadIdx.x;
    int lane = tid & 63;
    int wid = tid >> 6;
    int wr = wid >> 1, wc = wid & 1;

    int rowA0 = baseA + ti * 128;
    int rowB0 = baseB + tj * 128;

    int srow = tid >> 2;                // 0..63
    int scol = (tid & 3) * 8;           // 0,8,16,24 (shorts)

    // clamped (<=4095) staging row pointers; OOB rows masked in epilogue
    const unsigned short* pa0 = A + (size_t)min(rowA0 + srow,      4095) * DIM + scol;
    const unsigned short* pa1 = A + (size_t)min(rowA0 + srow + 64, 4095) * DIM + scol;
    const unsigned short* pb0 = B + (size_t)min(rowB0 + srow,      4095) * DIM + scol;
    const unsigned short* pb1 = B + (size_t)min(rowB0 + srow + 64, 4095) * DIM + scol;

    f32x4 accf[4][4];
#pragma unroll
    for (int m = 0; m < 4; ++m)
#pragma unroll
        for (int n = 0; n < 4; ++n) accf[m][n] = (f32x4)(0.f);

    int lr = lane & 15;
    int lk = (lane >> 4) * 8;

#define STAGE(buf, kt)                                                            \
    do {                                                                          \
        int k0_ = (kt) * 32;                                                      \
        __builtin_amdgcn_global_load_lds((const GLOBAL_AS void*)(pa0 + k0_),      \
            (LDS_AS void*)(As[buf] + tid * 8), 16, 0, 0);                         \
        __builtin_amdgcn_global_load_lds((const GLOBAL_AS void*)(pa1 + k0_),      \
            (LDS_AS void*)(As[buf] + 2048 + tid * 8), 16, 0, 0);                  \
        __builtin_amdgcn_global_load_lds((const GLOBAL_AS void*)(pb0 + k0_),      \
            (LDS_AS void*)(Bs[buf] + tid * 8), 16, 0, 0);                         \
        __builtin_amdgcn_global_load_lds((const GLOBAL_AS void*)(pb1 + k0_),      \
            (LDS_AS void*)(Bs[buf] + 2048 + tid * 8), 16, 0, 0);                  \
    } while (0)

#define COMPUTE(buf)                                                              \
    do {                                                                          \
        bf16x8 af[4], bfr[4];                                                     \
        _Pragma("unroll")                                                         \
        for (int f = 0; f < 4; ++f)                                               \
            af[f] = *(const bf16x8*)(As[buf] + (wr * 64 + f * 16 + lr) * 32 + lk);\
        _Pragma("unroll")                                                         \
        for (int f = 0; f < 4; ++f)                                               \
            bfr[f] = *(const bf16x8*)(Bs[buf] + (wc * 64 + f * 16 + lr) * 32 + lk);\
        _Pragma("unroll")                                                         \
        for (int m = 0; m < 4; ++m)                                               \
            _Pragma("unroll")                                                     \
            for (int n = 0; n < 4; ++n)                                           \
                accf[m][n] = __builtin_amdgcn_mfma_f32_16x16x32_bf16(             \
                    af[m], bfr[n], accf[m][n], 0, 0, 0);                          \
    } while (0)

    STAGE(0, 0);
    asm volatile("s_waitcnt vmcnt(0)");
    __syncthreads();

    int cur = 0;
    for (int kt = 0; kt < DIM / 32 - 1; ++kt) {
        STAGE(cur ^ 1, kt + 1);     // next tile's loads fly during compute
        COMPUTE(cur);
        __syncthreads();            // drains vmcnt(0)+lgkmcnt(0); next buf ready
        cur ^= 1;
    }
    COMPUTE(cur);

    // ---- fused epilogue: d2 -> K^2 -> weighted accumulate (single scalar) ----
    int rowBase = rowA0 + wr * 64;
    int colBase = rowB0 + wc * 64;

    float cn[4], cw[4];
#pragma unroll
    for (int f = 0; f < 4; ++f) {
        int gj = colBase + f * 16 + lr;
        int gjc = min(gj, 4095);
        cn[f] = nB[gjc];
        cw[f] = (gj < 4096 && cB[gjc] == cls) ? wB[gjc] : 0.0f;
    }

    const float NEGF = (-2.0f / (2.0f * 32.0f * 32.0f + 1e-8f)) * 1.44269504088896340736f;
    float lacc = 0.f;

#pragma unroll
    for (int m = 0; m < 4; ++m) {
#pragma unroll
        for (int j = 0; j < 4; ++j) {
            int gi = rowBase + m * 16 + (lane >> 4) * 4 + j;
            int gic = min(gi, 4095);
            float rn = nA[gic];
            float rw = (gi < 4096 && cA[gic] == cls) ? wA[gic] : 0.0f;
#pragma unroll
            for (int n = 0; n < 4; ++n) {
                float dot = accf[m][n][j];
                float d2 = rn + cn[n] - 2.0f * dot;
                d2 = fmaxf(d2, 0.0f);
                float k2 = exp2f(d2 * NEGF);        // = K^2
                lacc += k2 * rw * cw[n];
            }
        }
    }

    if (tid == 0) sred = 0.f;
    __syncthreads();
    for (int off = 32; off; off >>= 1) lacc += __shfl_xor(lacc, off);
    if (lane == 0) atomicAdd(&sred, lacc);
    __syncthreads();
    if (tid == 0) atomicAdd(outp, factor * sred);
#undef STAGE
#undef COMPUTE
}

__global__ void finalize_kernel(const float* __restrict__ acc, const int* __restrict__ ctrl,
                                float* __restrict__ out) {
    if (threadIdx.x != 0 || blockIdx.x != 0) return;
    const double EPS = 1e-8;
    const double LOG2 = 0.6931471805599453;
    double loss_cls = (double)acc[0] / NS_ROWS;
    double loss_ent = -(double)acc[1] / NT_ROWS;
    double creda_sum = 0.0, n_valid = 0.0;
    for (int c = 0; c < NC; ++c) {
        int nsc_i = ctrl[c], ntc_i = ctrl[4 + c];
        double nsc = (double)nsc_i, trt = acc[10 + c];
        double sss = acc[14 + c], sst = acc[18 + c], ssst = acc[22 + c];
        double trs = nsc;
        double info_s = sss / ((trs + EPS) * (trs + EPS));
        double h_s = -log(info_s + EPS) / LOG2;
        double info_t = sst / ((trt + EPS) * (trt + EPS));
        double h_t = -log(info_t + EPS) / LOG2;
        double trm = trs + trt;
        double ssm = sss + 2.0 * ssst + sst;
        double info_m = ssm / ((trm + EPS) * (trm + EPS));
        double h_m = -log(info_m + EPS) / LOG2;
        double pc = h_m - 0.5 * (h_s + h_t);
        if (nsc_i >= 2 && ntc_i >= 2) { creda_sum += pc; n_valid += 1.0; }
    }
    double creda = (n_valid > 0.0) ? creda_sum / n_valid : 0.0;
    out[0] = (float)(loss_cls + 1.0 * creda + 0.1 * loss_ent);
}

extern "C" void kernel_launch(void* const* d_in, const int* in_sizes, int n_in,
                              void* d_out, int out_size, void* d_ws, size_t ws_size,
                              hipStream_t stream) {
    const float* FS = (const float*)d_in[0];
    const float* LS = (const float*)d_in[1];
    const float* FT = (const float*)d_in[2];
    const float* LT = (const float*)d_in[3];
    const int* LAB = (const int*)d_in[4];

    char* ws = (char*)d_ws;
    unsigned short* fs = (unsigned short*)(ws);                       // 8 MB
    unsigned short* ft = (unsigned short*)(ws + 8388608);             // 8 MB
    char* p = ws + 16777216;
    float* nS  = (float*)(p);              // 16 KB
    float* wS  = (float*)(p + 16384);
    int*   cS  = (int*)  (p + 32768);
    float* nT  = (float*)(p + 49152);
    float* wT  = (float*)(p + 65536);
    int*   cT  = (int*)  (p + 81920);
    int*   clsT_tmp = (int*)  (p + 98304);
    float* wt2_tmp  = (float*)(p + 114688);
    int*   ctrl = (int*)  (p + 131072);        // 28 ints
    float* acc  = (float*)(p + 131072 + 128);  // 26 floats
    int4*  wl   = (int4*) (p + 131072 + 512);  // NWORK_MAX x 16 B
    int*   dstS = (int*)  (p + 131072 + 512 + NWORK_MAX * 16);
    int*   dstT = dstS + NS_ROWS;

    hipMemsetAsync(ctrl, 0, 256, stream);  // zeroes ctrl (counts) + acc

    prep_rows<<<32, 256, 0, stream>>>(LS, LAB, LT, clsT_tmp, wt2_tmp, ctrl, acc);
    aux_build<<<1, 64, 0, stream>>>(ctrl, wl);
    rank_rows<<<2, 1024, 0, stream>>>(LAB, clsT_tmp, ctrl, dstS, dstT);
    scatter_feat<<<NS_ROWS + NT_ROWS, 128, 0, stream>>>(FS, FT, LAB, clsT_tmp, wt2_tmp,
                                                        dstS, dstT, fs, ft,
                                                        nS, wS, cS, nT, wT, cT);
    gemm_reduce<<<NWORK_MAX, 256, 0, stream>>>(fs, ft, nS, wS, cS, nT, wT, cT,
                                               ctrl, wl, acc);
    finalize_kernel<<<1, 1, 0, stream>>>(acc, ctrl, (float*)d_out);
}

// Round 6
// 82.896 us; speedup vs baseline: 2.1204x; 1.0962x over previous
//
#include <hip/hip_runtime.h>
#include <cstdint>
#include <cstddef>

#define NS_ROWS 4096
#define NT_ROWS 4096
#define DIM 1024
#define NC 4
#define NWORK_MAX 2432
#define ACC_N 26

typedef __attribute__((ext_vector_type(4))) float f32x4;
typedef long long i64;

#define GLOBAL_AS __attribute__((address_space(1)))
#define LDS_AS __attribute__((address_space(3)))

// ---------------- ws layout ----------------
// fs (fp8 e4m3, class-permuted source rows) @ 0        4,194,304 B
// ft (fp8 e4m3, class-permuted target rows) @ 4194304  4,194,304 B
// p = ws + 8388608:
//   nS@0 wS@16K cS@32K nT@48K wT@64K cT@80K clsT_tmp@96K wt2_tmp@112K  (16 KB each)
//   ctrl@128K (28 ints)  acc@128K+128 (26 f)  wl@128K+512 (NWORK_MAX int4)
//   dstS@after wl  dstT@+16K
// ctrl ints: [0..3]cntS [4..7]cntT [16..19]baseS [20..23]baseT [24]nwork

// Per-row logits work: CE(source), entropy/w2/tr_t (target). Counts live in rank_rows.
__global__ void prep_rows(const float* __restrict__ LS, const int* __restrict__ labels,
                          const float* __restrict__ LT,
                          float* __restrict__ wt2_tmp, float* __restrict__ acc) {
    __shared__ float sacc[ACC_N];
    int t = threadIdx.x;
    if (t < ACC_N) sacc[t] = 0.f;
    __syncthreads();
    int gid = blockIdx.x * 256 + t;
    const float EPSF = 1e-8f;
    if (gid < NS_ROWS) {
        float4 l = ((const float4*)LS)[gid];
        float m = fmaxf(fmaxf(l.x, l.y), fmaxf(l.z, l.w));
        float e = expf(l.x - m) + expf(l.y - m) + expf(l.z - m) + expf(l.w - m);
        float lse = m + logf(e);
        int lab = labels[gid];
        float ll = (lab == 0) ? l.x : (lab == 1) ? l.y : (lab == 2) ? l.z : l.w;
        atomicAdd(&sacc[0], lse - ll);
    } else {
        int j = gid - NS_ROWS;
        float4 l = ((const float4*)LT)[j];
        float m = fmaxf(fmaxf(l.x, l.y), fmaxf(l.z, l.w));
        float p0 = expf(l.x - m), p1 = expf(l.y - m), p2 = expf(l.z - m), p3 = expf(l.w - m);
        float s = p0 + p1 + p2 + p3;
        p0 /= s; p1 /= s; p2 /= s; p3 /= s;
        float ent = p0 * logf(p0 + EPSF) + p1 * logf(p1 + EPSF) +
                    p2 * logf(p2 + EPSF) + p3 * logf(p3 + EPSF);
        int am = 0; float bm = p0;
        if (p1 > bm) { bm = p1; am = 1; }
        if (p2 > bm) { bm = p2; am = 2; }
        if (p3 > bm) { bm = p3; am = 3; }
        float sumsq = p0 * p0 + p1 * p1 + p2 * p2 + p3 * p3;
        const float INV_LOG2 = 1.44269504088896340736f;
        float h2 = -logf(sumsq + EPSF) * INV_LOG2;
        float w = 1.0f - h2 / (2.0f + EPSF);
        float w2 = w * w;
        wt2_tmp[j] = w2;
        atomicAdd(&sacc[1], ent);
        atomicAdd(&sacc[10 + am], w2);
    }
    __syncthreads();
    if (t < ACC_N && sacc[t] != 0.f) atomicAdd(&acc[t], sacc[t]);
}

// Deterministic counting-sort rank + per-class counts/bases + acc zeroing.
// block 0: source (labels). block 1: target (argmax of raw logits == argmax probs).
// 4 rows/thread; per-class counts packed 4x16-bit in u64; Hillis-Steele scan.
__global__ void rank_rows(const int* __restrict__ labels, const float* __restrict__ LT,
                          int* __restrict__ clsT_tmp, int* __restrict__ ctrl,
                          float* __restrict__ acc,
                          int* __restrict__ dstS, int* __restrict__ dstT) {
    __shared__ unsigned long long sdata[1024];
    int t = threadIdx.x;
    bool isS = (blockIdx.x == 0);
    int* dst = isS ? dstS : dstT;

    int c4[4];
    if (isS) {
        int4 lab4 = ((const int4*)labels)[t];
        c4[0] = lab4.x; c4[1] = lab4.y; c4[2] = lab4.z; c4[3] = lab4.w;
        if (t < ACC_N) acc[t] = 0.f;     // zero accumulators (prep_rows runs after)
    } else {
#pragma unroll
        for (int i = 0; i < 4; ++i) {
            float4 l = ((const float4*)LT)[t * 4 + i];
            int am = 0; float bm = l.x;
            if (l.y > bm) { bm = l.y; am = 1; }
            if (l.z > bm) { bm = l.z; am = 2; }
            if (l.w > bm) { bm = l.w; am = 3; }
            c4[i] = am;
            clsT_tmp[t * 4 + i] = am;
        }
    }
    unsigned long long packed = 0ULL;
#pragma unroll
    for (int i = 0; i < 4; ++i) packed += 1ULL << (c4[i] * 16);
    sdata[t] = packed;
    __syncthreads();
    for (int off = 1; off < 1024; off <<= 1) {
        unsigned long long v = sdata[t];
        unsigned long long add = (t >= off) ? sdata[t - off] : 0ULL;
        __syncthreads();
        sdata[t] = v + add;
        __syncthreads();
    }
    unsigned long long tot = sdata[1023];            // per-class totals (broadcast)
    unsigned long long ex = (t > 0) ? sdata[t - 1] : 0ULL;
    int baseC[NC]; int b = 0;
#pragma unroll
    for (int c = 0; c < NC; ++c) {
        baseC[c] = b;
        b += (int)((tot >> (c * 16)) & 0xFFFFULL);
    }
    if (t == 0) {
#pragma unroll
        for (int c = 0; c < NC; ++c) {
            ctrl[(isS ? 0 : 4) + c] = (int)((tot >> (c * 16)) & 0xFFFFULL);
            ctrl[(isS ? 16 : 20) + c] = baseC[c];
        }
    }
    int pref[NC];
#pragma unroll
    for (int c = 0; c < NC; ++c)
        pref[c] = (int)((ex >> (c * 16)) & 0xFFFFULL) + baseC[c];
#pragma unroll
    for (int i = 0; i < 4; ++i) {
        int c = c4[i];
        dst[t * 4 + i] = pref[c]++;
    }
}

// Build per-class tile work list, CLASS-MAJOR so consecutive work items share
// panels (XCD-chunked consumption keeps a class pair inside one XCD's L2).
__global__ void aux_build(int* __restrict__ ctrl, int4* __restrict__ wl) {
    if (threadIdx.x != 0) return;
    int n = 0;
    for (int c = 0; c < NC; ++c) {
        int Ts = (ctrl[c] + 127) >> 7;
        int Tt = (ctrl[4 + c] + 127) >> 7;
        for (int tj = 0; tj < Ts; ++tj)
            for (int ti = 0; ti <= tj; ++ti) wl[n++] = make_int4(0, c, ti, tj);
        for (int tj = 0; tj < Tt; ++tj)
            for (int ti = 0; ti <= tj; ++ti) wl[n++] = make_int4(1, c, ti, tj);
        for (int ti = 0; ti < Ts; ++ti)
            for (int tj = 0; tj < Tt; ++tj) wl[n++] = make_int4(2, c, ti, tj);
    }
    ctrl[24] = n;   // <= 2380 < NWORK_MAX
}

// fp8-convert (e4m3 RNE via HW cvt) + row norms OF THE QUANTIZED rows,
// scattered to class-contiguous buffers via the precomputed rank (no atomics).
__global__ void scatter_feat(const float* __restrict__ FS, const float* __restrict__ FT,
                             const int* __restrict__ labels,
                             const int* __restrict__ clsT_tmp, const float* __restrict__ wt2_tmp,
                             const int* __restrict__ dstS, const int* __restrict__ dstT,
                             unsigned char* __restrict__ fs, unsigned char* __restrict__ ft,
                             float* __restrict__ nS, float* __restrict__ wS, int* __restrict__ cS,
                             float* __restrict__ nT, float* __restrict__ wT, int* __restrict__ cT) {
    int b = blockIdx.x;
    int t = threadIdx.x;
    bool isS = b < NS_ROWS;
    int r = isS ? b : b - NS_ROWS;
    int cls = isS ? labels[r] : clsT_tmp[r];
    int dst = isS ? dstS[r] : dstT[r];
    __shared__ float partial[2];
    const float* src = (isS ? FS : FT) + (size_t)r * DIM;
    float4 v0 = ((const float4*)src)[t * 2];
    float4 v1 = ((const float4*)src)[t * 2 + 1];
    int p0 = 0, p1 = 0;
    p0 = __builtin_amdgcn_cvt_pk_fp8_f32(v0.x, v0.y, p0, false);
    p0 = __builtin_amdgcn_cvt_pk_fp8_f32(v0.z, v0.w, p0, true);
    p1 = __builtin_amdgcn_cvt_pk_fp8_f32(v1.x, v1.y, p1, false);
    p1 = __builtin_amdgcn_cvt_pk_fp8_f32(v1.z, v1.w, p1, true);
    float q[8];
    q[0] = __builtin_amdgcn_cvt_f32_fp8(p0, 0);
    q[1] = __builtin_amdgcn_cvt_f32_fp8(p0, 1);
    q[2] = __builtin_amdgcn_cvt_f32_fp8(p0, 2);
    q[3] = __builtin_amdgcn_cvt_f32_fp8(p0, 3);
    q[4] = __builtin_amdgcn_cvt_f32_fp8(p1, 0);
    q[5] = __builtin_amdgcn_cvt_f32_fp8(p1, 1);
    q[6] = __builtin_amdgcn_cvt_f32_fp8(p1, 2);
    q[7] = __builtin_amdgcn_cvt_f32_fp8(p1, 3);
    float ssum = 0.f;
#pragma unroll
    for (int i = 0; i < 8; ++i) ssum += q[i] * q[i];

    unsigned char* fdst = (isS ? fs : ft) + (size_t)dst * DIM;
    *(uint2*)(fdst + (size_t)t * 8) = make_uint2((unsigned)p0, (unsigned)p1);

    for (int off = 32; off; off >>= 1) ssum += __shfl_xor(ssum, off);
    if ((t & 63) == 0) partial[t >> 6] = ssum;
    __syncthreads();
    if (t == 0) {
        float nrm = partial[0] + partial[1];
        if (isS) { nS[dst] = nrm; wS[dst] = 1.0f; cS[dst] = cls; }
        else     { nT[dst] = nrm; wT[dst] = wt2_tmp[r]; cT[dst] = cls; }
    }
}

// Fused fp8 GEMM (A@B^T) + RBF + weighted reduction over class-partitioned tiles.
// 128x128 tile, 4 waves (2x2 of 64x64), BK=32, mfma_f32_16x16x32_fp8_fp8,
// 2-phase double-buffered pipeline; LDS 16.4KB -> ~8 blocks/CU resident.
// XCD-chunked work mapping: consecutive work items land on the same XCD.
__global__ __launch_bounds__(256, 4)
void gemm_reduce(const unsigned char* __restrict__ fs, const unsigned char* __restrict__ ft,
                 const float* __restrict__ nS, const float* __restrict__ wS, const int* __restrict__ cS,
                 const float* __restrict__ nT, const float* __restrict__ wT, const int* __restrict__ cT,
                 const int* __restrict__ ctrl, const int4* __restrict__ wl,
                 float* __restrict__ acc) {
    __shared__ unsigned char As[2][128 * 32];
    __shared__ unsigned char Bs[2][128 * 32];
    __shared__ float sred;

    int nwork = ctrl[24];
    int chunk = (nwork + 7) >> 3;
    int sub = blockIdx.x >> 3, xcd = blockIdx.x & 7;
    if (sub >= chunk) return;
    int widx = xcd * chunk + sub;          // XCD x gets work [x*chunk, (x+1)*chunk)
    if (widx >= nwork) return;
    int4 it = wl[widx];
    int kind = it.x, cls = it.y, ti = it.z, tj = it.w;

    const unsigned char *A, *B;
    const float *nA, *nB, *wA, *wB;
    const int *cA, *cB;
    int baseA, baseB;
    if (kind == 0)      { A = fs; B = fs; nA = nS; nB = nS; wA = wS; wB = wS; cA = cS; cB = cS;
                          baseA = ctrl[16 + cls]; baseB = baseA; }
    else if (kind == 1) { A = ft; B = ft; nA = nT; nB = nT; wA = wT; wB = wT; cA = cT; cB = cT;
                          baseA = ctrl[20 + cls]; baseB = baseA; }
    else                { A = fs; B = ft; nA = nS; nB = nT; wA = wS; cA = cS; cB = cT;
                          wB = wS;   // ss_st is mask-only on both sides; wS is all-ones
                          baseA = ctrl[16 + cls]; baseB = ctrl[20 + cls]; }
    float* outp = acc + 14 + kind * 4 + cls;
    float factor = (kind != 2 && ti != tj) ? 2.0f : 1.0f;

    int tid = threadIdx.x;
    int lane = tid & 63;
    int wid = tid >> 6;
    int wr = wid >> 1, wc = wid & 1;

    int rowA0 = baseA + ti * 128;
    int rowB0 = baseB + tj * 128;

    int srow = tid >> 1;                // 0..127
    int sb = (tid & 1) * 16;            // byte offset within 32B K-slice

    // clamp (<=4095) keeps staging inside real data (never NaN); masked in epilogue
    const unsigned char* pa = A + (size_t)min(rowA0 + srow, 4095) * DIM + sb;
    const unsigned char* pb = B + (size_t)min(rowB0 + srow, 4095) * DIM + sb;

    f32x4 accf[4][4];
#pragma unroll
    for (int m = 0; m < 4; ++m)
#pragma unroll
        for (int n = 0; n < 4; ++n) accf[m][n] = (f32x4)(0.f);

    int lr = lane & 15;
    int lk = (lane >> 4) * 8;           // byte offset of this lane's K-octet

#define STAGE(buf, kt)                                                            \
    do {                                                                          \
        int k0_ = (kt) * 32;                                                      \
        __builtin_amdgcn_global_load_lds((const GLOBAL_AS void*)(pa + k0_),       \
            (LDS_AS void*)(As[buf] + tid * 16), 16, 0, 0);                        \
        __builtin_amdgcn_global_load_lds((const GLOBAL_AS void*)(pb + k0_),       \
            (LDS_AS void*)(Bs[buf] + tid * 16), 16, 0, 0);                        \
    } while (0)

#define COMPUTE(buf)                                                              \
    do {                                                                          \
        i64 af[4], bfr[4];                                                        \
        _Pragma("unroll")                                                         \
        for (int f = 0; f < 4; ++f)                                               \
            af[f] = *(const i64*)(As[buf] + (wr * 64 + f * 16 + lr) * 32 + lk);   \
        _Pragma("unroll")                                                         \
        for (int f = 0; f < 4; ++f)                                               \
            bfr[f] = *(const i64*)(Bs[buf] + (wc * 64 + f * 16 + lr) * 32 + lk);  \
        _Pragma("unroll")                                                         \
        for (int m = 0; m < 4; ++m)                                               \
            _Pragma("unroll")                                                     \
            for (int n = 0; n < 4; ++n)                                           \
                accf[m][n] = __builtin_amdgcn_mfma_f32_16x16x32_fp8_fp8(          \
                    af[m], bfr[n], accf[m][n], 0, 0, 0);                          \
    } while (0)

    STAGE(0, 0);
    asm volatile("s_waitcnt vmcnt(0)");
    __syncthreads();

    int cur = 0;
    for (int kt = 0; kt < DIM / 32 - 1; ++kt) {
        STAGE(cur ^ 1, kt + 1);     // next tile's loads fly during compute
        COMPUTE(cur);
        __syncthreads();            // drains vmcnt(0)+lgkmcnt(0); next buf ready
        cur ^= 1;
    }
    COMPUTE(cur);

    // ---- fused epilogue: d2 -> K^2 -> weighted accumulate ----
    int rowBase = rowA0 + wr * 64;
    int colBase = rowB0 + wc * 64;

    float cn[4], cw[4];
#pragma unroll
    for (int f = 0; f < 4; ++f) {
        int gj = colBase + f * 16 + lr;
        int gjc = min(gj, 4095);
        cn[f] = nB[gjc];
        cw[f] = (gj < 4096 && cB[gjc] == cls) ? wB[gjc] : 0.0f;
    }

    const float NEGF = (-2.0f / (2.0f * 32.0f * 32.0f + 1e-8f)) * 1.44269504088896340736f;
    float lacc = 0.f;

#pragma unroll
    for (int m = 0; m < 4; ++m) {
#pragma unroll
        for (int j = 0; j < 4; ++j) {
            int gi = rowBase + m * 16 + (lane >> 4) * 4 + j;
            int gic = min(gi, 4095);
            float rn = nA[gic];
            float rw = (gi < 4096 && cA[gic] == cls) ? wA[gic] : 0.0f;
#pragma unroll
            for (int n = 0; n < 4; ++n) {
                float dot = accf[m][n][j];
                float d2 = rn + cn[n] - 2.0f * dot;
                d2 = fmaxf(d2, 0.0f);
                float k2 = exp2f(d2 * NEGF);        // = K^2
                lacc += k2 * rw * cw[n];
            }
        }
    }

    if (tid == 0) sred = 0.f;
    __syncthreads();
    for (int off = 32; off; off >>= 1) lacc += __shfl_xor(lacc, off);
    if (lane == 0) atomicAdd(&sred, lacc);
    __syncthreads();
    if (tid == 0) atomicAdd(outp, factor * sred);
#undef STAGE
#undef COMPUTE
}

__global__ void finalize_kernel(const float* __restrict__ acc, const int* __restrict__ ctrl,
                                float* __restrict__ out) {
    if (threadIdx.x != 0 || blockIdx.x != 0) return;
    const double EPS = 1e-8;
    const double LOG2 = 0.6931471805599453;
    double loss_cls = (double)acc[0] / NS_ROWS;
    double loss_ent = -(double)acc[1] / NT_ROWS;
    double creda_sum = 0.0, n_valid = 0.0;
    for (int c = 0; c < NC; ++c) {
        int nsc_i = ctrl[c], ntc_i = ctrl[4 + c];
        double nsc = (double)nsc_i, trt = acc[10 + c];
        double sss = acc[14 + c], sst = acc[18 + c], ssst = acc[22 + c];
        double trs = nsc;
        double info_s = sss / ((trs + EPS) * (trs + EPS));
        double h_s = -log(info_s + EPS) / LOG2;
        double info_t = sst / ((trt + EPS) * (trt + EPS));
        double h_t = -log(info_t + EPS) / LOG2;
        double trm = trs + trt;
        double ssm = sss + 2.0 * ssst + sst;
        double info_m = ssm / ((trm + EPS) * (trm + EPS));
        double h_m = -log(info_m + EPS) / LOG2;
        double pc = h_m - 0.5 * (h_s + h_t);
        if (nsc_i >= 2 && ntc_i >= 2) { creda_sum += pc; n_valid += 1.0; }
    }
    double creda = (n_valid > 0.0) ? creda_sum / n_valid : 0.0;
    out[0] = (float)(loss_cls + 1.0 * creda + 0.1 * loss_ent);
}

extern "C" void kernel_launch(void* const* d_in, const int* in_sizes, int n_in,
                              void* d_out, int out_size, void* d_ws, size_t ws_size,
                              hipStream_t stream) {
    const float* FS = (const float*)d_in[0];
    const float* LS = (const float*)d_in[1];
    const float* FT = (const float*)d_in[2];
    const float* LT = (const float*)d_in[3];
    const int* LAB = (const int*)d_in[4];

    char* ws = (char*)d_ws;
    unsigned char* fs = (unsigned char*)(ws);                 // 4 MB
    unsigned char* ft = (unsigned char*)(ws + 4194304);       // 4 MB
    char* p = ws + 8388608;
    float* nS  = (float*)(p);
    float* wS  = (float*)(p + 16384);
    int*   cS  = (int*)  (p + 32768);
    float* nT  = (float*)(p + 49152);
    float* wT  = (float*)(p + 65536);
    int*   cT  = (int*)  (p + 81920);
    int*   clsT_tmp = (int*)  (p + 98304);
    float* wt2_tmp  = (float*)(p + 114688);
    int*   ctrl = (int*)  (p + 131072);        // 28 ints
    float* acc  = (float*)(p + 131072 + 128);  // 26 floats
    int4*  wl   = (int4*) (p + 131072 + 512);  // NWORK_MAX x 16 B
    int*   dstS = (int*)  (p + 131072 + 512 + NWORK_MAX * 16);
    int*   dstT = dstS + NS_ROWS;

    // rank zeroes acc and writes counts/bases -> no memset needed
    rank_rows<<<2, 1024, 0, stream>>>(LAB, LT, clsT_tmp, ctrl, acc, dstS, dstT);
    aux_build<<<1, 64, 0, stream>>>(ctrl, wl);
    prep_rows<<<32, 256, 0, stream>>>(LS, LAB, LT, wt2_tmp, acc);
    scatter_feat<<<NS_ROWS + NT_ROWS, 128, 0, stream>>>(FS, FT, LAB, clsT_tmp, wt2_tmp,
                                                        dstS, dstT, fs, ft,
                                                        nS, wS, cS, nT, wT, cT);
    gemm_reduce<<<NWORK_MAX, 256, 0, stream>>>(fs, ft, nS, wS, cS, nT, wT, cT,
                                               ctrl, wl, acc);
    finalize_kernel<<<1, 1, 0, stream>>>(acc, ctrl, (float*)d_out);
}

// Round 8
// 70.238 us; speedup vs baseline: 2.5026x; 1.1802x over previous
//
#include <hip/hip_runtime.h>
#include <cstdint>
#include <cstddef>

#define NS_ROWS 4096
#define NT_ROWS 4096
#define DIM 1024
#define NC 4
#define NWORK_MAX 2432
#define ACC_N 26

typedef __attribute__((ext_vector_type(4))) float f32x4;
typedef long long i64;

#define GLOBAL_AS __attribute__((address_space(1)))
#define LDS_AS __attribute__((address_space(3)))

// ---------------- ws layout ----------------
// fs (fp8 e4m3, class-permuted source rows) @ 0        4,194,304 B
// ft (fp8 e4m3, class-permuted target rows) @ 4194304  4,194,304 B
// p = ws + 8388608:
//   nS@0 wS@16K cS@32K nT@48K wT@64K cT@80K  (16 KB each)
//   ctrl@96K (28 ints)  acc@96K+128 (26 f)  wl@96K+512 (NWORK_MAX int4)
//   dstS@after wl  dstT@+16K
// ctrl ints: [0..3]cntS [4..7]cntT [16..19]baseS [20..23]baseT [24]nwork

__device__ __forceinline__ int argmax4(float4 l) {
    int am = 0; float bm = l.x;
    if (l.y > bm) { bm = l.y; am = 1; }
    if (l.z > bm) { bm = l.z; am = 2; }
    if (l.w > bm) { bm = l.w; am = 3; }
    return am;
}

// Per-row logits work: CE(source), entropy + tr_t (target).
__global__ void prep_rows(const float* __restrict__ LS, const int* __restrict__ labels,
                          const float* __restrict__ LT, float* __restrict__ acc) {
    __shared__ float sacc[ACC_N];
    int t = threadIdx.x;
    if (t < ACC_N) sacc[t] = 0.f;
    __syncthreads();
    int gid = blockIdx.x * 256 + t;
    const float EPSF = 1e-8f;
    if (gid < NS_ROWS) {
        float4 l = ((const float4*)LS)[gid];
        float m = fmaxf(fmaxf(l.x, l.y), fmaxf(l.z, l.w));
        float e = expf(l.x - m) + expf(l.y - m) + expf(l.z - m) + expf(l.w - m);
        float lse = m + logf(e);
        int lab = labels[gid];
        float ll = (lab == 0) ? l.x : (lab == 1) ? l.y : (lab == 2) ? l.z : l.w;
        atomicAdd(&sacc[0], lse - ll);
    } else {
        int j = gid - NS_ROWS;
        float4 l = ((const float4*)LT)[j];
        float m = fmaxf(fmaxf(l.x, l.y), fmaxf(l.z, l.w));
        float p0 = expf(l.x - m), p1 = expf(l.y - m), p2 = expf(l.z - m), p3 = expf(l.w - m);
        float s = p0 + p1 + p2 + p3;
        p0 /= s; p1 /= s; p2 /= s; p3 /= s;
        float ent = p0 * logf(p0 + EPSF) + p1 * logf(p1 + EPSF) +
                    p2 * logf(p2 + EPSF) + p3 * logf(p3 + EPSF);
        int am = argmax4(l);
        float sumsq = p0 * p0 + p1 * p1 + p2 * p2 + p3 * p3;
        const float INV_LOG2 = 1.44269504088896340736f;
        float h2 = -logf(sumsq + EPSF) * INV_LOG2;
        float w = 1.0f - h2 / (2.0f + EPSF);
        atomicAdd(&sacc[1], ent);
        atomicAdd(&sacc[10 + am], w * w);
    }
    __syncthreads();
    if (t < ACC_N && sacc[t] != 0.f) atomicAdd(&acc[t], sacc[t]);
}

// Deterministic counting-sort rank + per-class counts/bases + acc zeroing.
// block 0: source (labels). block 1: target (argmax of raw logits).
// 4 rows/thread; per-class counts packed 4x16-bit in u64; Hillis-Steele scan.
__global__ void rank_rows(const int* __restrict__ labels, const float* __restrict__ LT,
                          int* __restrict__ ctrl, float* __restrict__ acc,
                          int* __restrict__ dstS, int* __restrict__ dstT) {
    __shared__ unsigned long long sdata[1024];
    int t = threadIdx.x;
    bool isS = (blockIdx.x == 0);
    int* dst = isS ? dstS : dstT;

    int c4[4];
    if (isS) {
        int4 lab4 = ((const int4*)labels)[t];
        c4[0] = lab4.x; c4[1] = lab4.y; c4[2] = lab4.z; c4[3] = lab4.w;
        if (t < ACC_N) acc[t] = 0.f;     // zero accumulators (prep_rows runs after)
    } else {
#pragma unroll
        for (int i = 0; i < 4; ++i)
            c4[i] = argmax4(((const float4*)LT)[t * 4 + i]);
    }
    unsigned long long packed = 0ULL;
#pragma unroll
    for (int i = 0; i < 4; ++i) packed += 1ULL << (c4[i] * 16);
    sdata[t] = packed;
    __syncthreads();
    for (int off = 1; off < 1024; off <<= 1) {
        unsigned long long v = sdata[t];
        unsigned long long add = (t >= off) ? sdata[t - off] : 0ULL;
        __syncthreads();
        sdata[t] = v + add;
        __syncthreads();
    }
    unsigned long long tot = sdata[1023];            // per-class totals (broadcast)
    unsigned long long ex = (t > 0) ? sdata[t - 1] : 0ULL;
    int baseC[NC]; int b = 0;
#pragma unroll
    for (int c = 0; c < NC; ++c) {
        baseC[c] = b;
        b += (int)((tot >> (c * 16)) & 0xFFFFULL);
    }
    if (t == 0) {
#pragma unroll
        for (int c = 0; c < NC; ++c) {
            ctrl[(isS ? 0 : 4) + c] = (int)((tot >> (c * 16)) & 0xFFFFULL);
            ctrl[(isS ? 16 : 20) + c] = baseC[c];
        }
    }
    int pref[NC];
#pragma unroll
    for (int c = 0; c < NC; ++c)
        pref[c] = (int)((ex >> (c * 16)) & 0xFFFFULL) + baseC[c];
#pragma unroll
    for (int i = 0; i < 4; ++i) {
        int c = c4[i];
        dst[t * 4 + i] = pref[c]++;
    }
}

// Parallel worklist build: 12 threads, one per (class, kind) segment.
// Class-major order preserved (XCD-chunked consumption => L2 locality).
__global__ void aux_build(const int* __restrict__ ctrl, int4* __restrict__ wl,
                          int* __restrict__ ctrl_w) {
    int t = threadIdx.x;
    int Ts[NC], Tt[NC];
#pragma unroll
    for (int c = 0; c < NC; ++c) {
        Ts[c] = (ctrl[c] + 127) >> 7;
        Tt[c] = (ctrl[4 + c] + 127) >> 7;
    }
    // segment sizes, class-major, kinds 0,1,2 within a class
    int segSize[12];
#pragma unroll
    for (int c = 0; c < NC; ++c) {
        segSize[c * 3 + 0] = Ts[c] * (Ts[c] + 1) / 2;
        segSize[c * 3 + 1] = Tt[c] * (Tt[c] + 1) / 2;
        segSize[c * 3 + 2] = Ts[c] * Tt[c];
    }
    if (t == 0) {
        int n = 0;
        for (int s = 0; s < 12; ++s) n += segSize[s];
        ctrl_w[24] = n;
    }
    if (t >= 12) return;
    int base = 0;
    for (int s = 0; s < t; ++s) base += segSize[s];
    int c = t / 3, kind = t % 3;
    int4* w = wl + base;
    int n = 0;
    if (kind == 0) {
        for (int tj = 0; tj < Ts[c]; ++tj)
            for (int ti = 0; ti <= tj; ++ti) w[n++] = make_int4(0, c, ti, tj);
    } else if (kind == 1) {
        for (int tj = 0; tj < Tt[c]; ++tj)
            for (int ti = 0; ti <= tj; ++ti) w[n++] = make_int4(1, c, ti, tj);
    } else {
        for (int ti = 0; ti < Ts[c]; ++ti)
            for (int tj = 0; tj < Tt[c]; ++tj) w[n++] = make_int4(2, c, ti, tj);
    }
}

// fp8-convert (e4m3 via HW cvt) + row norms OF THE QUANTIZED rows, scattered to
// class-contiguous buffers. One WAVE per row (64 lanes x 16 B): no LDS, no syncs.
// grid = 2048 blocks x 256 threads (4 waves = 4 rows per block).
__global__ void scatter_feat(const float* __restrict__ FS, const float* __restrict__ FT,
                             const int* __restrict__ labels, const float* __restrict__ LT,
                             const int* __restrict__ dstS, const int* __restrict__ dstT,
                             unsigned char* __restrict__ fs, unsigned char* __restrict__ ft,
                             float* __restrict__ nS, float* __restrict__ wS, int* __restrict__ cS,
                             float* __restrict__ nT, float* __restrict__ wT, int* __restrict__ cT) {
    int row = blockIdx.x * 4 + (threadIdx.x >> 6);
    int lane = threadIdx.x & 63;
    bool isS = row < NS_ROWS;
    int r = isS ? row : row - NS_ROWS;
    int dst = isS ? dstS[r] : dstT[r];      // same addr across wave -> broadcast

    const float* src = (isS ? FS : FT) + (size_t)r * DIM;
    float4 v0 = ((const float4*)src)[lane * 4 + 0];
    float4 v1 = ((const float4*)src)[lane * 4 + 1];
    float4 v2 = ((const float4*)src)[lane * 4 + 2];
    float4 v3 = ((const float4*)src)[lane * 4 + 3];
    int w0 = 0, w1 = 0, w2 = 0, w3 = 0;
    w0 = __builtin_amdgcn_cvt_pk_fp8_f32(v0.x, v0.y, w0, false);
    w0 = __builtin_amdgcn_cvt_pk_fp8_f32(v0.z, v0.w, w0, true);
    w1 = __builtin_amdgcn_cvt_pk_fp8_f32(v1.x, v1.y, w1, false);
    w1 = __builtin_amdgcn_cvt_pk_fp8_f32(v1.z, v1.w, w1, true);
    w2 = __builtin_amdgcn_cvt_pk_fp8_f32(v2.x, v2.y, w2, false);
    w2 = __builtin_amdgcn_cvt_pk_fp8_f32(v2.z, v2.w, w2, true);
    w3 = __builtin_amdgcn_cvt_pk_fp8_f32(v3.x, v3.y, w3, false);
    w3 = __builtin_amdgcn_cvt_pk_fp8_f32(v3.z, v3.w, w3, true);

    // dequant for norm: selector must be a LITERAL (front-end checks before unroll)
    float ssum = 0.f;
#define ACCQ(wv)                                                       \
    do {                                                               \
        float q0 = __builtin_amdgcn_cvt_f32_fp8((wv), 0);              \
        float q1 = __builtin_amdgcn_cvt_f32_fp8((wv), 1);              \
        float q2 = __builtin_amdgcn_cvt_f32_fp8((wv), 2);              \
        float q3 = __builtin_amdgcn_cvt_f32_fp8((wv), 3);              \
        ssum += q0 * q0 + q1 * q1 + q2 * q2 + q3 * q3;                 \
    } while (0)
    ACCQ(w0); ACCQ(w1); ACCQ(w2); ACCQ(w3);
#undef ACCQ

    unsigned char* fdst = (isS ? fs : ft) + (size_t)dst * DIM;
    *(uint4*)(fdst + lane * 16) = make_uint4((unsigned)w0, (unsigned)w1,
                                             (unsigned)w2, (unsigned)w3);

    for (int off = 32; off; off >>= 1) ssum += __shfl_xor(ssum, off);

    if (lane == 0) {
        if (isS) {
            nS[dst] = ssum; wS[dst] = 1.0f; cS[dst] = labels[r];
        } else {
            float4 l = ((const float4*)LT)[r];
            int am = argmax4(l);
            float m = fmaxf(fmaxf(l.x, l.y), fmaxf(l.z, l.w));
            float p0 = expf(l.x - m), p1 = expf(l.y - m),
                  p2 = expf(l.z - m), p3 = expf(l.w - m);
            float s = p0 + p1 + p2 + p3;
            float sumsq = (p0 * p0 + p1 * p1 + p2 * p2 + p3 * p3) / (s * s);
            const float INV_LOG2 = 1.44269504088896340736f;
            float h2 = -logf(sumsq + 1e-8f) * INV_LOG2;
            float w = 1.0f - h2 / (2.0f + 1e-8f);
            nT[dst] = ssum; wT[dst] = w * w; cT[dst] = am;
        }
    }
}

// Fused fp8 GEMM (A@B^T) + RBF + weighted reduction over class-partitioned tiles.
// 128x128 tile, 4 waves (2x2 of 64x64), BK=32, mfma_f32_16x16x32_fp8_fp8,
// 2-phase double-buffered pipeline; XCD-chunked work mapping.
__global__ __launch_bounds__(256, 4)
void gemm_reduce(const unsigned char* __restrict__ fs, const unsigned char* __restrict__ ft,
                 const float* __restrict__ nS, const float* __restrict__ wS, const int* __restrict__ cS,
                 const float* __restrict__ nT, const float* __restrict__ wT, const int* __restrict__ cT,
                 const int* __restrict__ ctrl, const int4* __restrict__ wl,
                 float* __restrict__ acc) {
    __shared__ unsigned char As[2][128 * 32];
    __shared__ unsigned char Bs[2][128 * 32];
    __shared__ float sred;

    int nwork = ctrl[24];
    int chunk = (nwork + 7) >> 3;
    int sub = blockIdx.x >> 3, xcd = blockIdx.x & 7;
    if (sub >= chunk) return;
    int widx = xcd * chunk + sub;          // XCD x gets work [x*chunk, (x+1)*chunk)
    if (widx >= nwork) return;
    int4 it = wl[widx];
    int kind = it.x, cls = it.y, ti = it.z, tj = it.w;

    const unsigned char *A, *B;
    const float *nA, *nB, *wA, *wB;
    const int *cA, *cB;
    int baseA, baseB;
    if (kind == 0)      { A = fs; B = fs; nA = nS; nB = nS; wA = wS; wB = wS; cA = cS; cB = cS;
                          baseA = ctrl[16 + cls]; baseB = baseA; }
    else if (kind == 1) { A = ft; B = ft; nA = nT; nB = nT; wA = wT; wB = wT; cA = cT; cB = cT;
                          baseA = ctrl[20 + cls]; baseB = baseA; }
    else                { A = fs; B = ft; nA = nS; nB = nT; wA = wS; cA = cS; cB = cT;
                          wB = wS;   // ss_st is mask-only on both sides; wS is all-ones
                          baseA = ctrl[16 + cls]; baseB = ctrl[20 + cls]; }
    float* outp = acc + 14 + kind * 4 + cls;
    float factor = (kind != 2 && ti != tj) ? 2.0f : 1.0f;

    int tid = threadIdx.x;
    int lane = tid & 63;
    int wid = tid >> 6;
    int wr = wid >> 1, wc = wid & 1;

    int rowA0 = baseA + ti * 128;
    int rowB0 = baseB + tj * 128;

    int srow = tid >> 1;                // 0..127
    int sb = (tid & 1) * 16;            // byte offset within 32B K-slice

    // clamp (<=4095) keeps staging inside real data (never junk); masked in epilogue
    const unsigned char* pa = A + (size_t)min(rowA0 + srow, 4095) * DIM + sb;
    const unsigned char* pb = B + (size_t)min(rowB0 + srow, 4095) * DIM + sb;

    f32x4 accf[4][4];
#pragma unroll
    for (int m = 0; m < 4; ++m)
#pragma unroll
        for (int n = 0; n < 4; ++n) accf[m][n] = (f32x4)(0.f);

    int lr = lane & 15;
    int lk = (lane >> 4) * 8;           // byte offset of this lane's K-octet

#define STAGE(buf, kt)                                                            \
    do {                                                                          \
        int k0_ = (kt) * 32;                                                      \
        __builtin_amdgcn_global_load_lds((const GLOBAL_AS void*)(pa + k0_),       \
            (LDS_AS void*)(As[buf] + tid * 16), 16, 0, 0);                        \
        __builtin_amdgcn_global_load_lds((const GLOBAL_AS void*)(pb + k0_),       \
            (LDS_AS void*)(Bs[buf] + tid * 16), 16, 0, 0);                        \
    } while (0)

#define COMPUTE(buf)                                                              \
    do {                                                                          \
        i64 af[4], bfr[4];                                                        \
        _Pragma("unroll")                                                         \
        for (int f = 0; f < 4; ++f)                                               \
            af[f] = *(const i64*)(As[buf] + (wr * 64 + f * 16 + lr) * 32 + lk);   \
        _Pragma("unroll")                                                         \
        for (int f = 0; f < 4; ++f)                                               \
            bfr[f] = *(const i64*)(Bs[buf] + (wc * 64 + f * 16 + lr) * 32 + lk);  \
        _Pragma("unroll")                                                         \
        for (int m = 0; m < 4; ++m)                                               \
            _Pragma("unroll")                                                     \
            for (int n = 0; n < 4; ++n)                                           \
                accf[m][n] = __builtin_amdgcn_mfma_f32_16x16x32_fp8_fp8(          \
                    af[m], bfr[n], accf[m][n], 0, 0, 0);                          \
    } while (0)

    STAGE(0, 0);
    asm volatile("s_waitcnt vmcnt(0)");
    __syncthreads();

    int cur = 0;
    for (int kt = 0; kt < DIM / 32 - 1; ++kt) {
        STAGE(cur ^ 1, kt + 1);     // next tile's loads fly during compute
        COMPUTE(cur);
        __syncthreads();            // drains vmcnt(0)+lgkmcnt(0); next buf ready
        cur ^= 1;
    }
    COMPUTE(cur);

    // ---- fused epilogue: d2 -> K^2 -> weighted accumulate ----
    int rowBase = rowA0 + wr * 64;
    int colBase = rowB0 + wc * 64;

    float cn[4], cw[4];
#pragma unroll
    for (int f = 0; f < 4; ++f) {
        int gj = colBase + f * 16 + lr;
        int gjc = min(gj, 4095);
        cn[f] = nB[gjc];
        cw[f] = (gj < 4096 && cB[gjc] == cls) ? wB[gjc] : 0.0f;
    }

    const float NEGF = (-2.0f / (2.0f * 32.0f * 32.0f + 1e-8f)) * 1.44269504088896340736f;
    float lacc = 0.f;

#pragma unroll
    for (int m = 0; m < 4; ++m) {
#pragma unroll
        for (int j = 0; j < 4; ++j) {
            int gi = rowBase + m * 16 + (lane >> 4) * 4 + j;
            int gic = min(gi, 4095);
            float rn = nA[gic];
            float rw = (gi < 4096 && cA[gic] == cls) ? wA[gic] : 0.0f;
#pragma unroll
            for (int n = 0; n < 4; ++n) {
                float dot = accf[m][n][j];
                float d2 = rn + cn[n] - 2.0f * dot;
                d2 = fmaxf(d2, 0.0f);
                float k2 = exp2f(d2 * NEGF);        // = K^2
                lacc += k2 * rw * cw[n];
            }
        }
    }

    if (tid == 0) sred = 0.f;
    __syncthreads();
    for (int off = 32; off; off >>= 1) lacc += __shfl_xor(lacc, off);
    if (lane == 0) atomicAdd(&sred, lacc);
    __syncthreads();
    if (tid == 0) atomicAdd(outp, factor * sred);
#undef STAGE
#undef COMPUTE
}

__global__ void finalize_kernel(const float* __restrict__ acc, const int* __restrict__ ctrl,
                                float* __restrict__ out) {
    if (threadIdx.x != 0 || blockIdx.x != 0) return;
    const double EPS = 1e-8;
    const double LOG2 = 0.6931471805599453;
    double loss_cls = (double)acc[0] / NS_ROWS;
    double loss_ent = -(double)acc[1] / NT_ROWS;
    double creda_sum = 0.0, n_valid = 0.0;
    for (int c = 0; c < NC; ++c) {
        int nsc_i = ctrl[c], ntc_i = ctrl[4 + c];
        double nsc = (double)nsc_i, trt = acc[10 + c];
        double sss = acc[14 + c], sst = acc[18 + c], ssst = acc[22 + c];
        double trs = nsc;
        double info_s = sss / ((trs + EPS) * (trs + EPS));
        double h_s = -log(info_s + EPS) / LOG2;
        double info_t = sst / ((trt + EPS) * (trt + EPS));
        double h_t = -log(info_t + EPS) / LOG2;
        double trm = trs + trt;
        double ssm = sss + 2.0 * ssst + sst;
        double info_m = ssm / ((trm + EPS) * (trm + EPS));
        double h_m = -log(info_m + EPS) / LOG2;
        double pc = h_m - 0.5 * (h_s + h_t);
        if (nsc_i >= 2 && ntc_i >= 2) { creda_sum += pc; n_valid += 1.0; }
    }
    double creda = (n_valid > 0.0) ? creda_sum / n_valid : 0.0;
    out[0] = (float)(loss_cls + 1.0 * creda + 0.1 * loss_ent);
}

extern "C" void kernel_launch(void* const* d_in, const int* in_sizes, int n_in,
                              void* d_out, int out_size, void* d_ws, size_t ws_size,
                              hipStream_t stream) {
    const float* FS = (const float*)d_in[0];
    const float* LS = (const float*)d_in[1];
    const float* FT = (const float*)d_in[2];
    const float* LT = (const float*)d_in[3];
    const int* LAB = (const int*)d_in[4];

    char* ws = (char*)d_ws;
    unsigned char* fs = (unsigned char*)(ws);                 // 4 MB
    unsigned char* ft = (unsigned char*)(ws + 4194304);       // 4 MB
    char* p = ws + 8388608;
    float* nS  = (float*)(p);
    float* wS  = (float*)(p + 16384);
    int*   cS  = (int*)  (p + 32768);
    float* nT  = (float*)(p + 49152);
    float* wT  = (float*)(p + 65536);
    int*   cT  = (int*)  (p + 81920);
    int*   ctrl = (int*)  (p + 98304);        // 28 ints
    float* acc  = (float*)(p + 98304 + 128);  // 26 floats
    int4*  wl   = (int4*) (p + 98304 + 512);  // NWORK_MAX x 16 B
    int*   dstS = (int*)  (p + 98304 + 512 + NWORK_MAX * 16);
    int*   dstT = dstS + NS_ROWS;

    // rank zeroes acc and writes counts/bases -> no memset needed
    rank_rows<<<2, 1024, 0, stream>>>(LAB, LT, ctrl, acc, dstS, dstT);
    aux_build<<<1, 64, 0, stream>>>(ctrl, wl, ctrl);
    prep_rows<<<32, 256, 0, stream>>>(LS, LAB, LT, acc);
    scatter_feat<<<2048, 256, 0, stream>>>(FS, FT, LAB, LT, dstS, dstT, fs, ft,
                                           nS, wS, cS, nT, wT, cT);
    gemm_reduce<<<NWORK_MAX, 256, 0, stream>>>(fs, ft, nS, wS, cS, nT, wT, cT,
                                               ctrl, wl, acc);
    finalize_kernel<<<1, 1, 0, stream>>>(acc, ctrl, (float*)d_out);
}